// Round 1
// baseline (524.697 us; speedup 1.0000x reference)
//
#include <hip/hip_runtime.h>
#include <hip/hip_bf16.h>

#define T_TOK 16384
#define DMODEL 768
#define DFF 3072
#define NEXP 4
#define ROWPAD 512

typedef __attribute__((ext_vector_type(8))) short bf16x8;
typedef __attribute__((ext_vector_type(4))) float f32x4;

__device__ __forceinline__ void gl_lds16(const void* g, void* l) {
  __builtin_amdgcn_global_load_lds(
      (const __attribute__((address_space(1))) unsigned int*)g,
      (__attribute__((address_space(3))) unsigned int*)l, 16, 0, 0);
}

__device__ __forceinline__ short f2bf(float f) {
  union { float f; unsigned u; } v; v.f = f;
  unsigned r = v.u + 0x7fff + ((v.u >> 16) & 1);   // RTNE
  return (short)(r >> 16);
}

__device__ __forceinline__ float gelu_f(float x) {
  const float c = 0.7978845608028654f;              // sqrt(2/pi), tanh-approx gelu (JAX default)
  float z = c * (x + 0.044715f * x * x * x);
  z = fminf(fmaxf(z, -15.f), 15.f);
  float e = __expf(-2.f * z);
  return 0.5f * x * (1.f + (1.f - e) / (1.f + e));
}

// aligned expert offsets (multiples of 128 so tile-row parity == global-row parity)
__device__ __forceinline__ int expert_aoff(const int* counts, int e) {
  int off = 0;
  for (int i = 0; i < e; ++i) off += (counts[i] + 127) & ~127;
  return off;
}

// ---------------- router: fp32 logits, softmax, argmax bucket ----------------
__global__ void router_kernel(const float* __restrict__ x, const float* __restrict__ Wg,
                              const float* __restrict__ bg, int* __restrict__ counts,
                              int* __restrict__ perm, float* __restrict__ gate) {
  int t = blockIdx.x * 4 + (threadIdx.x >> 6);
  int l = threadIdx.x & 63;
  const float* xr = x + (size_t)t * DMODEL;
  float s0 = 0.f, s1 = 0.f, s2 = 0.f, s3 = 0.f;
#pragma unroll
  for (int i = 0; i < DMODEL / 64; ++i) {
    int d = l + i * 64;
    float xv = xr[d];
    float4 w = *((const float4*)Wg + d);            // Wg[d][0..3]
    s0 += xv * w.x; s1 += xv * w.y; s2 += xv * w.z; s3 += xv * w.w;
  }
#pragma unroll
  for (int off = 32; off; off >>= 1) {
    s0 += __shfl_xor(s0, off);
    s1 += __shfl_xor(s1, off);
    s2 += __shfl_xor(s2, off);
    s3 += __shfl_xor(s3, off);
  }
  if (l == 0) {
    float lg[4] = { s0 + bg[0], s1 + bg[1], s2 + bg[2], s3 + bg[3] };
    int best = 0; float m = lg[0];
#pragma unroll
    for (int e = 1; e < 4; ++e) if (lg[e] > m) { m = lg[e]; best = e; }  // first-max like jnp.argmax
    float s = 0.f;
#pragma unroll
    for (int e = 0; e < 4; ++e) s += __expf(lg[e] - m);
    int pos = atomicAdd(&counts[best], 1);
    perm[best * T_TOK + pos] = t;
    gate[t] = 1.0f / s;                             // max softmax prob
  }
}

// ------------- gather x rows -> expert-contiguous bf16, swizzled -------------
__global__ void gather_kernel(const float* __restrict__ x, const int* __restrict__ counts,
                              const int* __restrict__ perm, const float* __restrict__ gate,
                              short* __restrict__ xg, int* __restrict__ tokg,
                              float* __restrict__ gateg) {
  int e = blockIdx.y;
  int cnt = counts[e];
  int pos = blockIdx.x * 8 + (threadIdx.x >> 5);
  if (pos >= cnt) return;
  int off = expert_aoff(counts, e);
  int t = perm[e * T_TOK + pos];
  int g = off + pos;
  int l = threadIdx.x & 31;
  const float* src = x + (size_t)t * DMODEL;
  short* dst = xg + (size_t)g * DMODEL;
  int sw = g & 7;
#pragma unroll
  for (int i = 0; i < 3; ++i) {
    int c = l + 32 * i;                              // 16B chunk index, 0..95
    float4 a = *((const float4*)src + c * 2);
    float4 b = *((const float4*)src + c * 2 + 1);
    bf16x8 v;
    v[0] = f2bf(a.x); v[1] = f2bf(a.y); v[2] = f2bf(a.z); v[3] = f2bf(a.w);
    v[4] = f2bf(b.x); v[5] = f2bf(b.y); v[6] = f2bf(b.z); v[7] = f2bf(b.w);
    int cs = (c & ~7) | ((c & 7) ^ sw);              // XOR-swizzle within 128B segment
    *(bf16x8*)(dst + cs * 8) = v;
  }
  if (l == 0) { tokg[g] = t; gateg[g] = gate[t]; }
}

// --------- transpose+convert: [E][K][N] fp32 -> [E][N][K] bf16 swizzled -------
__global__ void transpose_kernel(const float* __restrict__ src, short* __restrict__ dst,
                                 int K, int N) {
  __shared__ float lds[64 * 65];
  int e = blockIdx.z;
  int k0 = blockIdx.x * 64, n0 = blockIdx.y * 64;
  const float* s = src + (size_t)e * K * N;
  short* d = dst + (size_t)e * N * K;
#pragma unroll
  for (int i = 0; i < 16; ++i) {
    int idx = threadIdx.x + i * 256;
    int kk = idx >> 6, nn = idx & 63;
    lds[kk * 65 + nn] = s[(size_t)(k0 + kk) * N + n0 + nn];
  }
  __syncthreads();
#pragma unroll
  for (int i = 0; i < 2; ++i) {
    int cid = threadIdx.x + i * 256;
    int nn = cid >> 3, uu = cid & 7;
    int n = n0 + nn;
    bf16x8 v;
#pragma unroll
    for (int j = 0; j < 8; ++j) v[j] = f2bf(lds[(uu * 8 + j) * 65 + nn]);
    int cs = (k0 >> 3) + (uu ^ (n & 7));
    *(bf16x8*)(d + (size_t)n * K + cs * 8) = v;
  }
}

// ---------------- GEMM1: h = gelu(xg @ W1 + b1), bf16 out, swizzled ----------
__global__ __launch_bounds__(256, 2)
void gemm1_kernel(const short* __restrict__ xg, const short* __restrict__ w1t,
                  const float* __restrict__ b1, const int* __restrict__ counts,
                  short* __restrict__ h, int FFC, int chunk) {
  __shared__ __align__(16) short sA[128 * 64];
  __shared__ __align__(16) short sB[128 * 64];
  int e = blockIdx.z;
  int cnt = counts[e];
  int m0 = blockIdx.y * 128;
  if (m0 >= cnt) return;
  int off = expert_aoff(counts, e);
  int n0c = blockIdx.x * 128;
  int n0g = chunk * FFC + n0c;

  const char* Abase = (const char*)(xg + (size_t)(off + m0) * DMODEL);
  const char* Bbase = (const char*)(w1t + (size_t)e * DFF * DMODEL + (size_t)n0g * DMODEL);

  int wid = threadIdx.x >> 6, lane = threadIdx.x & 63;
  int wm = wid >> 1, wn = wid & 1;

  f32x4 acc[4][4];
#pragma unroll
  for (int i = 0; i < 4; ++i)
#pragma unroll
    for (int j = 0; j < 4; ++j) acc[i][j] = (f32x4){0.f, 0.f, 0.f, 0.f};

  for (int kt = 0; kt < DMODEL / 64; ++kt) {
    int kb = kt * 128;
#pragma unroll
    for (int r = 0; r < 4; ++r) {
      int o = wid * 1024 + r * 4096 + lane * 16;     // byte in 128x128B tile
      int row = o >> 7, b = o & 127;
      gl_lds16(Abase + (size_t)row * (DMODEL * 2) + kb + b, (char*)sA + wid * 1024 + r * 4096);
      gl_lds16(Bbase + (size_t)row * (DMODEL * 2) + kb + b, (char*)sB + wid * 1024 + r * 4096);
    }
    __syncthreads();
#pragma unroll
    for (int ks = 0; ks < 2; ++ks) {
      bf16x8 af[4], bfr[4];
      int u = ks * 4 + (lane >> 4);
#pragma unroll
      for (int mi = 0; mi < 4; ++mi) {
        int row = wm * 64 + mi * 16 + (lane & 15);
        af[mi] = *(const bf16x8*)&sA[row * 64 + ((u ^ (row & 7)) << 3)];
      }
#pragma unroll
      for (int ni = 0; ni < 4; ++ni) {
        int row = wn * 64 + ni * 16 + (lane & 15);
        bfr[ni] = *(const bf16x8*)&sB[row * 64 + ((u ^ (row & 7)) << 3)];
      }
#pragma unroll
      for (int mi = 0; mi < 4; ++mi)
#pragma unroll
        for (int ni = 0; ni < 4; ++ni)
          acc[mi][ni] = __builtin_amdgcn_mfma_f32_16x16x32_bf16(af[mi], bfr[ni], acc[mi][ni], 0, 0, 0);
    }
    __syncthreads();
  }

#pragma unroll
  for (int ni = 0; ni < 4; ++ni) {
    int coll = wn * 64 + ni * 16 + (lane & 15);
    int ng = n0g + coll;
    int nc = n0c + coll;
    float bb = b1[e * DFF + ng];
    int c = nc >> 3, o7 = nc & 7;
#pragma unroll
    for (int mi = 0; mi < 4; ++mi) {
      f32x4 v = acc[mi][ni];
#pragma unroll
      for (int r = 0; r < 4; ++r) {
        int ml = m0 + wm * 64 + mi * 16 + (lane >> 4) * 4 + r;
        if (ml < cnt) {
          int g = off + ml;
          int cs = (c & ~7) | ((c & 7) ^ (g & 7));
          h[(size_t)g * FFC + cs * 8 + o7] = f2bf(gelu_f(v[r] + bb));
        }
      }
    }
  }
}

// ------- GEMM2: out[tok] (+)= h @ W2 (+ b2, * gate on last chunk) ------------
__global__ __launch_bounds__(256, 2)
void gemm2_kernel(const short* __restrict__ h, const short* __restrict__ w2t,
                  const float* __restrict__ b2, const int* __restrict__ counts,
                  const int* __restrict__ tokg, const float* __restrict__ gateg,
                  float* __restrict__ out, int FFC, int chunk, int nchunks) {
  __shared__ __align__(16) short sA[128 * 64];
  __shared__ __align__(16) short sB[128 * 64];
  int e = blockIdx.z;
  int cnt = counts[e];
  int m0 = blockIdx.y * 128;
  if (m0 >= cnt) return;
  int off = expert_aoff(counts, e);
  int n0 = blockIdx.x * 128;

  const char* Abase = (const char*)(h + (size_t)(off + m0) * FFC);
  const char* Bbase = (const char*)(w2t + (size_t)e * DMODEL * DFF + (size_t)n0 * DFF + (size_t)chunk * FFC);

  int wid = threadIdx.x >> 6, lane = threadIdx.x & 63;
  int wm = wid >> 1, wn = wid & 1;

  f32x4 acc[4][4];
#pragma unroll
  for (int i = 0; i < 4; ++i)
#pragma unroll
    for (int j = 0; j < 4; ++j) acc[i][j] = (f32x4){0.f, 0.f, 0.f, 0.f};

  for (int kt = 0; kt < FFC / 64; ++kt) {
    int kb = kt * 128;
#pragma unroll
    for (int r = 0; r < 4; ++r) {
      int o = wid * 1024 + r * 4096 + lane * 16;
      int row = o >> 7, b = o & 127;
      gl_lds16(Abase + (size_t)row * (FFC * 2) + kb + b, (char*)sA + wid * 1024 + r * 4096);
      gl_lds16(Bbase + (size_t)row * (DFF * 2) + kb + b, (char*)sB + wid * 1024 + r * 4096);
    }
    __syncthreads();
#pragma unroll
    for (int ks = 0; ks < 2; ++ks) {
      bf16x8 af[4], bfr[4];
      int u = ks * 4 + (lane >> 4);
#pragma unroll
      for (int mi = 0; mi < 4; ++mi) {
        int row = wm * 64 + mi * 16 + (lane & 15);
        af[mi] = *(const bf16x8*)&sA[row * 64 + ((u ^ (row & 7)) << 3)];
      }
#pragma unroll
      for (int ni = 0; ni < 4; ++ni) {
        int row = wn * 64 + ni * 16 + (lane & 15);
        bfr[ni] = *(const bf16x8*)&sB[row * 64 + ((u ^ (row & 7)) << 3)];
      }
#pragma unroll
      for (int mi = 0; mi < 4; ++mi)
#pragma unroll
        for (int ni = 0; ni < 4; ++ni)
          acc[mi][ni] = __builtin_amdgcn_mfma_f32_16x16x32_bf16(af[mi], bfr[ni], acc[mi][ni], 0, 0, 0);
    }
    __syncthreads();
  }

#pragma unroll
  for (int ni = 0; ni < 4; ++ni) {
    int colg = n0 + wn * 64 + ni * 16 + (lane & 15);
    float bb = b2[e * DMODEL + colg];
#pragma unroll
    for (int mi = 0; mi < 4; ++mi) {
      f32x4 v = acc[mi][ni];
#pragma unroll
      for (int r = 0; r < 4; ++r) {
        int ml = m0 + wm * 64 + mi * 16 + (lane >> 4) * 4 + r;
        if (ml < cnt) {
          int g = off + ml;
          float* op = out + (size_t)tokg[g] * DMODEL + colg;
          float pv = v[r];
          if (chunk == 0 && nchunks > 1) {
            *op = pv;
          } else if (chunk < nchunks - 1) {
            *op += pv;
          } else {
            float prev = (nchunks > 1) ? *op : 0.f;
            *op = (prev + pv + bb) * gateg[g];
          }
        }
      }
    }
  }
}

extern "C" void kernel_launch(void* const* d_in, const int* in_sizes, int n_in,
                              void* d_out, int out_size, void* d_ws, size_t ws_size,
                              hipStream_t stream) {
  (void)in_sizes; (void)n_in; (void)out_size;
  const float* x  = (const float*)d_in[0];
  const float* Wg = (const float*)d_in[1];
  const float* bg = (const float*)d_in[2];
  const float* W1 = (const float*)d_in[3];
  const float* b1 = (const float*)d_in[4];
  const float* W2 = (const float*)d_in[5];
  const float* b2 = (const float*)d_in[6];
  float* out = (float*)d_out;
  char* ws = (char*)d_ws;

  size_t cur = 0;
  auto take = [&](size_t bytes) -> size_t {
    cur = (cur + 255) & ~(size_t)255;
    size_t r = cur; cur += bytes; return r;
  };
  size_t o_counts = take(64);
  size_t o_perm  = take((size_t)NEXP * T_TOK * 4);
  size_t o_gate  = take((size_t)T_TOK * 4);
  size_t o_tokg  = take((size_t)(T_TOK + ROWPAD) * 4);
  size_t o_gateg = take((size_t)(T_TOK + ROWPAD) * 4);
  size_t o_w1t   = take((size_t)NEXP * DFF * DMODEL * 2);
  size_t o_w2t   = take((size_t)NEXP * DMODEL * DFF * 2);
  size_t o_xg    = take((size_t)(T_TOK + ROWPAD) * DMODEL * 2);
  cur = (cur + 255) & ~(size_t)255;
  size_t o_h = cur;

  int FFC = 128;
  const int cands[6] = {3072, 1536, 768, 384, 256, 128};
  for (int i = 0; i < 6; ++i) {
    if (o_h + (size_t)(T_TOK + ROWPAD) * cands[i] * 2 <= ws_size) { FFC = cands[i]; break; }
  }

  int*   counts = (int*)(ws + o_counts);
  int*   perm   = (int*)(ws + o_perm);
  float* gate   = (float*)(ws + o_gate);
  int*   tokg   = (int*)(ws + o_tokg);
  float* gateg  = (float*)(ws + o_gateg);
  short* w1t    = (short*)(ws + o_w1t);
  short* w2t    = (short*)(ws + o_w2t);
  short* xg     = (short*)(ws + o_xg);
  short* hbuf   = (short*)(ws + o_h);

  hipMemsetAsync(counts, 0, 64, stream);
  router_kernel<<<T_TOK / 4, 256, 0, stream>>>(x, Wg, bg, counts, perm, gate);
  transpose_kernel<<<dim3(DMODEL / 64, DFF / 64, NEXP), 256, 0, stream>>>(W1, w1t, DMODEL, DFF);
  transpose_kernel<<<dim3(DFF / 64, DMODEL / 64, NEXP), 256, 0, stream>>>(W2, w2t, DFF, DMODEL);
  gather_kernel<<<dim3(T_TOK / 8, NEXP), 256, 0, stream>>>(x, counts, perm, gate, xg, tokg, gateg);

  int NC = DFF / FFC;
  for (int c = 0; c < NC; ++c) {
    gemm1_kernel<<<dim3(FFC / 128, T_TOK / 128, NEXP), 256, 0, stream>>>(xg, w1t, b1, counts, hbuf, FFC, c);
    gemm2_kernel<<<dim3(DMODEL / 128, T_TOK / 128, NEXP), 256, 0, stream>>>(hbuf, w2t, b2, counts, tokg, gateg, out, FFC, c, NC);
  }
}

// Round 2
// 344.792 us; speedup vs baseline: 1.5218x; 1.5218x over previous
//
#include <hip/hip_runtime.h>
#include <hip/hip_bf16.h>

#define T_TOK 16384
#define DMODEL 768
#define DFF 3072
#define NEXP 4
#define ROWPAD 512

typedef __attribute__((ext_vector_type(8))) short bf16x8;
typedef __attribute__((ext_vector_type(4))) float f32x4;

__device__ __forceinline__ void gl_lds16(const void* g, void* l) {
  __builtin_amdgcn_global_load_lds(
      (const __attribute__((address_space(1))) unsigned int*)g,
      (__attribute__((address_space(3))) unsigned int*)l, 16, 0, 0);
}

__device__ __forceinline__ short f2bf(float f) {
  union { float f; unsigned u; } v; v.f = f;
  unsigned r = v.u + 0x7fff + ((v.u >> 16) & 1);   // RTNE
  return (short)(r >> 16);
}

__device__ __forceinline__ float gelu_f(float x) {
  const float c = 0.7978845608028654f;              // sqrt(2/pi), tanh-approx gelu (JAX default)
  float z = c * (x + 0.044715f * x * x * x);
  z = fminf(fmaxf(z, -15.f), 15.f);
  float e = __expf(-2.f * z);
  return 0.5f * x * (1.f + (1.f - e) / (1.f + e));
}

// aligned expert offsets (multiples of 128 so tile-row parity == global-row parity)
__device__ __forceinline__ int expert_aoff(const int* counts, int e) {
  int off = 0;
  for (int i = 0; i < e; ++i) off += (counts[i] + 127) & ~127;
  return off;
}

// ---------------- route: fp32 logits, softmax, argmax — NO atomics ----------
__global__ void route_kernel(const float* __restrict__ x, const float* __restrict__ Wg,
                             const float* __restrict__ bg, int* __restrict__ route,
                             float* __restrict__ gate) {
  int t = blockIdx.x * 4 + (threadIdx.x >> 6);
  int l = threadIdx.x & 63;
  const float* xr = x + (size_t)t * DMODEL;
  float s0 = 0.f, s1 = 0.f, s2 = 0.f, s3 = 0.f;
#pragma unroll
  for (int i = 0; i < DMODEL / 64; ++i) {
    int d = l + i * 64;
    float xv = xr[d];
    float4 w = *((const float4*)Wg + d);            // Wg[d][0..3]
    s0 += xv * w.x; s1 += xv * w.y; s2 += xv * w.z; s3 += xv * w.w;
  }
#pragma unroll
  for (int off = 32; off; off >>= 1) {
    s0 += __shfl_xor(s0, off);
    s1 += __shfl_xor(s1, off);
    s2 += __shfl_xor(s2, off);
    s3 += __shfl_xor(s3, off);
  }
  if (l == 0) {
    float lg[4] = { s0 + bg[0], s1 + bg[1], s2 + bg[2], s3 + bg[3] };
    int best = 0; float m = lg[0];
#pragma unroll
    for (int e = 1; e < 4; ++e) if (lg[e] > m) { m = lg[e]; best = e; }  // first-max like jnp.argmax
    float s = 0.f;
#pragma unroll
    for (int e = 0; e < 4; ++e) s += __expf(lg[e] - m);
    route[t] = best;
    gate[t] = 1.0f / s;                             // max softmax prob
  }
}

// ---- bucket: ballot histogram + LDS prefix, 4 atomics per block (not 256) ---
__global__ void bucket_kernel(const int* __restrict__ route, int* __restrict__ counts,
                              int* __restrict__ perm) {
  __shared__ int wcnt[4][NEXP];
  __shared__ int wpre[4][NEXP];
  __shared__ int base[NEXP];
  int tid = threadIdx.x;
  int t = blockIdx.x * 256 + tid;
  int w = tid >> 6, l = tid & 63;
  int r = route[t];
  int lanepre = 0;
  unsigned long long lower = (l == 0) ? 0ull : (~0ull >> (64 - l));
#pragma unroll
  for (int e = 0; e < NEXP; ++e) {
    unsigned long long m = __ballot(r == e);
    if (l == 0) wcnt[w][e] = (int)__popcll(m);
    if (r == e) lanepre = (int)__popcll(m & lower);
  }
  __syncthreads();
  if (tid < NEXP) {
    int s = 0;
#pragma unroll
    for (int ww = 0; ww < 4; ++ww) { wpre[ww][tid] = s; s += wcnt[ww][tid]; }
    base[tid] = atomicAdd(&counts[tid], s);
  }
  __syncthreads();
  int pos = base[r] + wpre[w][r] + lanepre;
  perm[r * T_TOK + pos] = t;
}

// ------------- gather x rows -> expert-contiguous bf16, swizzled -------------
__global__ void gather_kernel(const float* __restrict__ x, const int* __restrict__ counts,
                              const int* __restrict__ perm, const float* __restrict__ gate,
                              short* __restrict__ xg, int* __restrict__ tokg,
                              float* __restrict__ gateg) {
  int e = blockIdx.y;
  int cnt = counts[e];
  int pos = blockIdx.x * 8 + (threadIdx.x >> 5);
  if (pos >= cnt) return;
  int off = expert_aoff(counts, e);
  int t = perm[e * T_TOK + pos];
  int g = off + pos;
  int l = threadIdx.x & 31;
  const float* src = x + (size_t)t * DMODEL;
  short* dst = xg + (size_t)g * DMODEL;
  int sw = g & 7;
#pragma unroll
  for (int i = 0; i < 3; ++i) {
    int c = l + 32 * i;                              // 16B chunk index, 0..95
    float4 a = *((const float4*)src + c * 2);
    float4 b = *((const float4*)src + c * 2 + 1);
    bf16x8 v;
    v[0] = f2bf(a.x); v[1] = f2bf(a.y); v[2] = f2bf(a.z); v[3] = f2bf(a.w);
    v[4] = f2bf(b.x); v[5] = f2bf(b.y); v[6] = f2bf(b.z); v[7] = f2bf(b.w);
    int cs = (c & ~7) | ((c & 7) ^ sw);              // XOR-swizzle within 128B segment
    *(bf16x8*)(dst + cs * 8) = v;
  }
  if (l == 0) { tokg[g] = t; gateg[g] = gate[t]; }
}

// --------- transpose+convert: [E][K][N] fp32 -> [E][N][K] bf16 swizzled -------
__global__ void transpose_kernel(const float* __restrict__ src, short* __restrict__ dst,
                                 int K, int N) {
  __shared__ float lds[64 * 65];
  int e = blockIdx.z;
  int k0 = blockIdx.x * 64, n0 = blockIdx.y * 64;
  const float* s = src + (size_t)e * K * N;
  short* d = dst + (size_t)e * N * K;
#pragma unroll
  for (int i = 0; i < 16; ++i) {
    int idx = threadIdx.x + i * 256;
    int kk = idx >> 6, nn = idx & 63;
    lds[kk * 65 + nn] = s[(size_t)(k0 + kk) * N + n0 + nn];
  }
  __syncthreads();
#pragma unroll
  for (int i = 0; i < 2; ++i) {
    int cid = threadIdx.x + i * 256;
    int nn = cid >> 3, uu = cid & 7;
    int n = n0 + nn;
    bf16x8 v;
#pragma unroll
    for (int j = 0; j < 8; ++j) v[j] = f2bf(lds[(uu * 8 + j) * 65 + nn]);
    int cs = (k0 >> 3) + (uu ^ (n & 7));
    *(bf16x8*)(d + (size_t)n * K + cs * 8) = v;
  }
}

// ---------------- GEMM1: h = gelu(xg @ W1 + b1), bf16 out, swizzled ----------
__global__ __launch_bounds__(256, 2)
void gemm1_kernel(const short* __restrict__ xg, const short* __restrict__ w1t,
                  const float* __restrict__ b1, const int* __restrict__ counts,
                  short* __restrict__ h, int FFC, int chunk) {
  __shared__ __align__(16) short sA[128 * 64];
  __shared__ __align__(16) short sB[128 * 64];
  int e = blockIdx.z;
  int cnt = counts[e];
  int m0 = blockIdx.y * 128;
  if (m0 >= cnt) return;
  int off = expert_aoff(counts, e);
  int n0c = blockIdx.x * 128;
  int n0g = chunk * FFC + n0c;

  const char* Abase = (const char*)(xg + (size_t)(off + m0) * DMODEL);
  const char* Bbase = (const char*)(w1t + (size_t)e * DFF * DMODEL + (size_t)n0g * DMODEL);

  int wid = threadIdx.x >> 6, lane = threadIdx.x & 63;
  int wm = wid >> 1, wn = wid & 1;

  f32x4 acc[4][4];
#pragma unroll
  for (int i = 0; i < 4; ++i)
#pragma unroll
    for (int j = 0; j < 4; ++j) acc[i][j] = (f32x4){0.f, 0.f, 0.f, 0.f};

  for (int kt = 0; kt < DMODEL / 64; ++kt) {
    int kb = kt * 128;
#pragma unroll
    for (int r = 0; r < 4; ++r) {
      int o = wid * 1024 + r * 4096 + lane * 16;     // byte in 128x128B tile
      int row = o >> 7, b = o & 127;
      gl_lds16(Abase + (size_t)row * (DMODEL * 2) + kb + b, (char*)sA + wid * 1024 + r * 4096);
      gl_lds16(Bbase + (size_t)row * (DMODEL * 2) + kb + b, (char*)sB + wid * 1024 + r * 4096);
    }
    __syncthreads();
#pragma unroll
    for (int ks = 0; ks < 2; ++ks) {
      bf16x8 af[4], bfr[4];
      int u = ks * 4 + (lane >> 4);
#pragma unroll
      for (int mi = 0; mi < 4; ++mi) {
        int row = wm * 64 + mi * 16 + (lane & 15);
        af[mi] = *(const bf16x8*)&sA[row * 64 + ((u ^ (row & 7)) << 3)];
      }
#pragma unroll
      for (int ni = 0; ni < 4; ++ni) {
        int row = wn * 64 + ni * 16 + (lane & 15);
        bfr[ni] = *(const bf16x8*)&sB[row * 64 + ((u ^ (row & 7)) << 3)];
      }
#pragma unroll
      for (int mi = 0; mi < 4; ++mi)
#pragma unroll
        for (int ni = 0; ni < 4; ++ni)
          acc[mi][ni] = __builtin_amdgcn_mfma_f32_16x16x32_bf16(af[mi], bfr[ni], acc[mi][ni], 0, 0, 0);
    }
    __syncthreads();
  }

#pragma unroll
  for (int ni = 0; ni < 4; ++ni) {
    int coll = wn * 64 + ni * 16 + (lane & 15);
    int ng = n0g + coll;
    int nc = n0c + coll;
    float bb = b1[e * DFF + ng];
    int c = nc >> 3, o7 = nc & 7;
#pragma unroll
    for (int mi = 0; mi < 4; ++mi) {
      f32x4 v = acc[mi][ni];
#pragma unroll
      for (int r = 0; r < 4; ++r) {
        int ml = m0 + wm * 64 + mi * 16 + (lane >> 4) * 4 + r;
        if (ml < cnt) {
          int g = off + ml;
          int cs = (c & ~7) | ((c & 7) ^ (g & 7));
          h[(size_t)g * FFC + cs * 8 + o7] = f2bf(gelu_f(v[r] + bb));
        }
      }
    }
  }
}

// ------- GEMM2: out[tok] (+)= h @ W2 (+ b2, * gate on last chunk) ------------
__global__ __launch_bounds__(256, 2)
void gemm2_kernel(const short* __restrict__ h, const short* __restrict__ w2t,
                  const float* __restrict__ b2, const int* __restrict__ counts,
                  const int* __restrict__ tokg, const float* __restrict__ gateg,
                  float* __restrict__ out, int FFC, int chunk, int nchunks) {
  __shared__ __align__(16) short sA[128 * 64];
  __shared__ __align__(16) short sB[128 * 64];
  int e = blockIdx.z;
  int cnt = counts[e];
  int m0 = blockIdx.y * 128;
  if (m0 >= cnt) return;
  int off = expert_aoff(counts, e);
  int n0 = blockIdx.x * 128;

  const char* Abase = (const char*)(h + (size_t)(off + m0) * FFC);
  const char* Bbase = (const char*)(w2t + (size_t)e * DMODEL * DFF + (size_t)n0 * DFF + (size_t)chunk * FFC);

  int wid = threadIdx.x >> 6, lane = threadIdx.x & 63;
  int wm = wid >> 1, wn = wid & 1;

  f32x4 acc[4][4];
#pragma unroll
  for (int i = 0; i < 4; ++i)
#pragma unroll
    for (int j = 0; j < 4; ++j) acc[i][j] = (f32x4){0.f, 0.f, 0.f, 0.f};

  for (int kt = 0; kt < FFC / 64; ++kt) {
    int kb = kt * 128;
#pragma unroll
    for (int r = 0; r < 4; ++r) {
      int o = wid * 1024 + r * 4096 + lane * 16;
      int row = o >> 7, b = o & 127;
      gl_lds16(Abase + (size_t)row * (FFC * 2) + kb + b, (char*)sA + wid * 1024 + r * 4096);
      gl_lds16(Bbase + (size_t)row * (DFF * 2) + kb + b, (char*)sB + wid * 1024 + r * 4096);
    }
    __syncthreads();
#pragma unroll
    for (int ks = 0; ks < 2; ++ks) {
      bf16x8 af[4], bfr[4];
      int u = ks * 4 + (lane >> 4);
#pragma unroll
      for (int mi = 0; mi < 4; ++mi) {
        int row = wm * 64 + mi * 16 + (lane & 15);
        af[mi] = *(const bf16x8*)&sA[row * 64 + ((u ^ (row & 7)) << 3)];
      }
#pragma unroll
      for (int ni = 0; ni < 4; ++ni) {
        int row = wn * 64 + ni * 16 + (lane & 15);
        bfr[ni] = *(const bf16x8*)&sB[row * 64 + ((u ^ (row & 7)) << 3)];
      }
#pragma unroll
      for (int mi = 0; mi < 4; ++mi)
#pragma unroll
        for (int ni = 0; ni < 4; ++ni)
          acc[mi][ni] = __builtin_amdgcn_mfma_f32_16x16x32_bf16(af[mi], bfr[ni], acc[mi][ni], 0, 0, 0);
    }
    __syncthreads();
  }

#pragma unroll
  for (int ni = 0; ni < 4; ++ni) {
    int colg = n0 + wn * 64 + ni * 16 + (lane & 15);
    float bb = b2[e * DMODEL + colg];
#pragma unroll
    for (int mi = 0; mi < 4; ++mi) {
      f32x4 v = acc[mi][ni];
#pragma unroll
      for (int r = 0; r < 4; ++r) {
        int ml = m0 + wm * 64 + mi * 16 + (lane >> 4) * 4 + r;
        if (ml < cnt) {
          int g = off + ml;
          float* op = out + (size_t)tokg[g] * DMODEL + colg;
          float pv = v[r];
          if (chunk == 0 && nchunks > 1) {
            *op = pv;
          } else if (chunk < nchunks - 1) {
            *op += pv;
          } else {
            float prev = (nchunks > 1) ? *op : 0.f;
            *op = (prev + pv + bb) * gateg[g];
          }
        }
      }
    }
  }
}

extern "C" void kernel_launch(void* const* d_in, const int* in_sizes, int n_in,
                              void* d_out, int out_size, void* d_ws, size_t ws_size,
                              hipStream_t stream) {
  (void)in_sizes; (void)n_in; (void)out_size;
  const float* x  = (const float*)d_in[0];
  const float* Wg = (const float*)d_in[1];
  const float* bg = (const float*)d_in[2];
  const float* W1 = (const float*)d_in[3];
  const float* b1 = (const float*)d_in[4];
  const float* W2 = (const float*)d_in[5];
  const float* b2 = (const float*)d_in[6];
  float* out = (float*)d_out;
  char* ws = (char*)d_ws;

  size_t cur = 0;
  auto take = [&](size_t bytes) -> size_t {
    cur = (cur + 255) & ~(size_t)255;
    size_t r = cur; cur += bytes; return r;
  };
  size_t o_counts = take(64);
  size_t o_perm  = take((size_t)NEXP * T_TOK * 4);
  size_t o_route = take((size_t)T_TOK * 4);
  size_t o_gate  = take((size_t)T_TOK * 4);
  size_t o_tokg  = take((size_t)(T_TOK + ROWPAD) * 4);
  size_t o_gateg = take((size_t)(T_TOK + ROWPAD) * 4);
  size_t o_w1t   = take((size_t)NEXP * DFF * DMODEL * 2);
  size_t o_w2t   = take((size_t)NEXP * DMODEL * DFF * 2);
  size_t o_xg    = take((size_t)(T_TOK + ROWPAD) * DMODEL * 2);
  cur = (cur + 255) & ~(size_t)255;
  size_t o_h = cur;

  int FFC = 128;
  const int cands[6] = {3072, 1536, 768, 384, 256, 128};
  for (int i = 0; i < 6; ++i) {
    if (o_h + (size_t)(T_TOK + ROWPAD) * cands[i] * 2 <= ws_size) { FFC = cands[i]; break; }
  }

  int*   counts = (int*)(ws + o_counts);
  int*   perm   = (int*)(ws + o_perm);
  int*   routeb = (int*)(ws + o_route);
  float* gate   = (float*)(ws + o_gate);
  int*   tokg   = (int*)(ws + o_tokg);
  float* gateg  = (float*)(ws + o_gateg);
  short* w1t    = (short*)(ws + o_w1t);
  short* w2t    = (short*)(ws + o_w2t);
  short* xg     = (short*)(ws + o_xg);
  short* hbuf   = (short*)(ws + o_h);

  hipMemsetAsync(counts, 0, 64, stream);
  route_kernel<<<T_TOK / 4, 256, 0, stream>>>(x, Wg, bg, routeb, gate);
  bucket_kernel<<<T_TOK / 256, 256, 0, stream>>>(routeb, counts, perm);
  transpose_kernel<<<dim3(DMODEL / 64, DFF / 64, NEXP), 256, 0, stream>>>(W1, w1t, DMODEL, DFF);
  transpose_kernel<<<dim3(DFF / 64, DMODEL / 64, NEXP), 256, 0, stream>>>(W2, w2t, DFF, DMODEL);
  gather_kernel<<<dim3(T_TOK / 8, NEXP), 256, 0, stream>>>(x, counts, perm, gate, xg, tokg, gateg);

  int NC = DFF / FFC;
  for (int c = 0; c < NC; ++c) {
    gemm1_kernel<<<dim3(FFC / 128, T_TOK / 128, NEXP), 256, 0, stream>>>(xg, w1t, b1, counts, hbuf, FFC, c);
    gemm2_kernel<<<dim3(DMODEL / 128, T_TOK / 128, NEXP), 256, 0, stream>>>(hbuf, w2t, b2, counts, tokg, gateg, out, FFC, c, NC);
  }
}